// Round 1
// baseline (793.512 us; speedup 1.0000x reference)
//
#include <hip/hip_runtime.h>

#define F_IN 256
#define CCH  128

// ---------------- GEMM: C[M,128] = act(A[M,K] @ W[128,K]^T + bias) ----------------
#define BM 128
#define BN 128
#define BK 16
#define TM 8
#define TN 8

template<bool RELU>
__global__ __launch_bounds__(256)
void gemm_tiled(const float* __restrict__ A, const float* __restrict__ W,
                const float* __restrict__ bias, float* __restrict__ Cmat,
                int M, int Kdim)
{
    __shared__ float As[BK][BM];
    __shared__ float Bs[BK][BN];
    const int tid = threadIdx.x;
    const int tx = tid & 15;   // col group (0..15) -> cols tx*8..+8
    const int ty = tid >> 4;   // row group (0..15) -> rows ty*8..+8
    const int m0 = blockIdx.x * BM;

    float acc[TM][TN];
#pragma unroll
    for (int i = 0; i < TM; i++)
#pragma unroll
        for (int j = 0; j < TN; j++) acc[i][j] = 0.f;

    for (int k0 = 0; k0 < Kdim; k0 += BK) {
        // Load A tile: 128 rows x 16 cols = 512 float4, 2 per thread
#pragma unroll
        for (int l = 0; l < 2; l++) {
            int f = tid + l * 256;
            int row = f >> 2, kq = f & 3;
            float4 a;
            if (m0 + row < M)
                a = *reinterpret_cast<const float4*>(&A[(long)(m0 + row) * Kdim + k0 + kq * 4]);
            else
                a = make_float4(0.f, 0.f, 0.f, 0.f);
            As[kq * 4 + 0][row] = a.x;
            As[kq * 4 + 1][row] = a.y;
            As[kq * 4 + 2][row] = a.z;
            As[kq * 4 + 3][row] = a.w;
        }
        // Load B tile: Bs[k][n] = W[n][k0+k]; W rows are contiguous in k
#pragma unroll
        for (int l = 0; l < 2; l++) {
            int f = tid + l * 256;
            int n = f >> 2, kq = f & 3;
            float4 b = *reinterpret_cast<const float4*>(&W[(long)n * Kdim + k0 + kq * 4]);
            Bs[kq * 4 + 0][n] = b.x;
            Bs[kq * 4 + 1][n] = b.y;
            Bs[kq * 4 + 2][n] = b.z;
            Bs[kq * 4 + 3][n] = b.w;
        }
        __syncthreads();
#pragma unroll
        for (int kk = 0; kk < BK; kk++) {
            float a[TM], b[TN];
            *(float4*)&a[0] = *(const float4*)&As[kk][ty * TM];
            *(float4*)&a[4] = *(const float4*)&As[kk][ty * TM + 4];
            *(float4*)&b[0] = *(const float4*)&Bs[kk][tx * TN];
            *(float4*)&b[4] = *(const float4*)&Bs[kk][tx * TN + 4];
#pragma unroll
            for (int i = 0; i < TM; i++)
#pragma unroll
                for (int j = 0; j < TN; j++) acc[i][j] += a[i] * b[j];
        }
        __syncthreads();
    }

    float bvals[TN];
#pragma unroll
    for (int j = 0; j < TN; j++) bvals[j] = bias ? bias[tx * TN + j] : 0.f;

#pragma unroll
    for (int i = 0; i < TM; i++) {
        int m = m0 + ty * TM + i;
        if (m < M) {
            float tmp[TN];
#pragma unroll
            for (int j = 0; j < TN; j++) {
                float v = acc[i][j] + bvals[j];
                if (RELU) v = fmaxf(v, 0.f);
                tmp[j] = v;
            }
            *(float4*)&Cmat[(long)m * CCH + tx * TN]     = *(float4*)&tmp[0];
            *(float4*)&Cmat[(long)m * CCH + tx * TN + 4] = *(float4*)&tmp[4];
        }
    }
}

// ---------------- degree / CSR build ----------------
__global__ void zero_cnt(int* cnt, int N) {
    int i = blockIdx.x * 256 + threadIdx.x;
    if (i < N) cnt[i] = 0;
}

__global__ void count_deg(const int* __restrict__ dst, int* __restrict__ cnt, int E) {
    int e = blockIdx.x * 256 + threadIdx.x;
    if (e < E) atomicAdd(&cnt[dst[e]], 1);
}

// chunk = 512 elements per block (block of 256 threads, 2 elems each)
__global__ void chunk_reduce(const int* __restrict__ cnt, int* __restrict__ csums, int N) {
    __shared__ int s[256];
    int t = threadIdx.x;
    int base = blockIdx.x * 512;
    int a = (base + t < N) ? cnt[base + t] : 0;
    int b = (base + 256 + t < N) ? cnt[base + 256 + t] : 0;
    s[t] = a + b;
    __syncthreads();
    for (int off = 128; off > 0; off >>= 1) {
        if (t < off) s[t] += s[t + off];
        __syncthreads();
    }
    if (t == 0) csums[blockIdx.x] = s[0];
}

__global__ void scan_chunks(const int* __restrict__ csums, int* __restrict__ coffs, int nchunks) {
    __shared__ int s[256];
    int t = threadIdx.x;
    int v = (t < nchunks) ? csums[t] : 0;
    s[t] = v;
    __syncthreads();
    for (int off = 1; off < 256; off <<= 1) {
        int x = (t >= off) ? s[t - off] : 0;
        __syncthreads();
        s[t] += x;
        __syncthreads();
    }
    if (t < nchunks) coffs[t] = s[t] - v;  // exclusive
}

__global__ __launch_bounds__(512)
void scan_within(const int* __restrict__ cnt, const int* __restrict__ coffs,
                 int* __restrict__ row_start, int* __restrict__ row_cur,
                 float* __restrict__ dinv, int N)
{
    __shared__ int s[512];
    int t = threadIdx.x;
    int i = blockIdx.x * 512 + t;
    int v = (i < N) ? cnt[i] : 0;
    s[t] = v;
    __syncthreads();
    for (int off = 1; off < 512; off <<= 1) {
        int x = (t >= off) ? s[t - off] : 0;
        __syncthreads();
        s[t] += x;
        __syncthreads();
    }
    if (i < N) {
        int excl = coffs[blockIdx.x] + s[t] - v;
        row_start[i] = excl;
        row_cur[i] = excl;
        dinv[i] = rsqrtf((float)v + 1.0f);   // deg = in-degree + self-loop >= 1
    }
}

__global__ void fill_csr(const int* __restrict__ src, const int* __restrict__ dst,
                         int* __restrict__ row_cur, int* __restrict__ csr, int E)
{
    int e = blockIdx.x * 256 + threadIdx.x;
    if (e < E) {
        int d = dst[e];
        int slot = atomicAdd(&row_cur[d], 1);
        csr[slot] = src[e];
    }
}

// ---------------- gather: out[n] = b2 + z[n]*dinv[n]^2 + sum_in z[s]*dinv[s]*dinv[n] ----------------
__global__ __launch_bounds__(256)
void gather_nodes(const float* __restrict__ z, const int* __restrict__ csr,
                  const int* __restrict__ row_start, const int* __restrict__ cnt,
                  const float* __restrict__ dinv, const float* __restrict__ b2,
                  float* __restrict__ out, int N)
{
    int node = blockIdx.x * 2 + (threadIdx.x >> 7);
    int c = threadIdx.x & 127;
    if (node >= N) return;
    float di = dinv[node];
    float acc = b2[c] + z[(long)node * CCH + c] * di * di;
    int rs = row_start[node];
    int ce = cnt[node];
    for (int j = 0; j < ce; j++) {
        int s = csr[rs + j];
        float w = dinv[s] * di;
        acc += z[(long)s * CCH + c] * w;
    }
    out[(long)node * CCH + c] = acc;
}

extern "C" void kernel_launch(void* const* d_in, const int* in_sizes, int n_in,
                              void* d_out, int out_size, void* d_ws, size_t ws_size,
                              hipStream_t stream)
{
    const float* x  = (const float*)d_in[0];
    const int*   ei = (const int*)d_in[1];
    const float* W1 = (const float*)d_in[2];
    const float* b1 = (const float*)d_in[3];
    const float* W2 = (const float*)d_in[4];
    const float* b2 = (const float*)d_in[5];
    float* out = (float*)d_out;

    const int N = in_sizes[0] / F_IN;
    const int E = in_sizes[1] / 2;
    const int* src = ei;
    const int* dst = ei + E;

    char* ws = (char*)d_ws;
    float* h   = (float*)ws;  ws += (size_t)N * CCH * 4;
    float* z   = (float*)ws;  ws += (size_t)N * CCH * 4;
    int* csr   = (int*)ws;    ws += (size_t)E * 4;
    int* cnt   = (int*)ws;    ws += (size_t)N * 4;
    int* rstart= (int*)ws;    ws += (size_t)N * 4;
    int* rcur  = (int*)ws;    ws += (size_t)N * 4;
    float* dinv= (float*)ws;  ws += (size_t)N * 4;
    int* csums = (int*)ws;    ws += 4096;
    int* coffs = (int*)ws;    ws += 4096;

    const int nchunks = (N + 511) / 512;   // 196 for N=100000 (fits one scan block)

    // degree + CSR build
    zero_cnt<<<(N + 255) / 256, 256, 0, stream>>>(cnt, N);
    count_deg<<<(E + 255) / 256, 256, 0, stream>>>(dst, cnt, E);
    chunk_reduce<<<nchunks, 256, 0, stream>>>(cnt, csums, N);
    scan_chunks<<<1, 256, 0, stream>>>(csums, coffs, nchunks);
    scan_within<<<nchunks, 512, 0, stream>>>(cnt, coffs, rstart, rcur, dinv, N);
    fill_csr<<<(E + 255) / 256, 256, 0, stream>>>(src, dst, rcur, csr, E);

    // h = relu(x @ W1^T + b1); z = h @ W2^T
    gemm_tiled<true ><<<(N + BM - 1) / BM, 256, 0, stream>>>(x, W1, b1, h, N, F_IN);
    gemm_tiled<false><<<(N + BM - 1) / BM, 256, 0, stream>>>(h, W2, nullptr, z, N, CCH);

    // aggregate
    gather_nodes<<<(N + 1) / 2, 256, 0, stream>>>(z, csr, rstart, cnt, dinv, b2, out, N);
}

// Round 2
// 577.480 us; speedup vs baseline: 1.3741x; 1.3741x over previous
//
#include <hip/hip_runtime.h>

#define F_IN 256
#define CCH  128

// ---------------- helpers: bf16 pack/unpack ----------------
__device__ __forceinline__ unsigned short f2bf(float f) {
    union { float f; unsigned i; } u; u.f = f;
    unsigned r = u.i + 0x7fffu + ((u.i >> 16) & 1u);   // RNE
    return (unsigned short)(r >> 16);
}
__device__ __forceinline__ unsigned packbf2(float lo, float hi) {
    return (unsigned)f2bf(lo) | ((unsigned)f2bf(hi) << 16);
}
__device__ __forceinline__ float2 bf2f2(unsigned u) {
    union { unsigned i; float f; } lo, hi;
    lo.i = u << 16;
    hi.i = u & 0xffff0000u;
    return make_float2(lo.f, hi.f);
}

// ---------------- GEMM: C[M,128] = epilogue(A[M,K] @ W[128,K]^T) ----------------
// MODE 0: C = relu(A@W^T + bias) stored fp32 (h)
// MODE 1: C = (A@W^T) * dinv[row]  stored packed bf16x2 (z')
#define BM 128
#define BN 128
#define BK 16
#define TM 8
#define TN 8

template<int MODE>
__global__ __launch_bounds__(256)
void gemm_tiled(const float* __restrict__ A, const float* __restrict__ W,
                const float* __restrict__ bias, const float* __restrict__ dinv,
                float* __restrict__ Cf, unsigned* __restrict__ Cq,
                int M, int Kdim)
{
    __shared__ float As[BK][BM];
    __shared__ float Bs[BK][BN];
    const int tid = threadIdx.x;
    const int tx = tid & 15;   // col group (0..15) -> cols tx*8..+8
    const int ty = tid >> 4;   // row group (0..15) -> rows ty*8..+8
    const int m0 = blockIdx.x * BM;

    float acc[TM][TN];
#pragma unroll
    for (int i = 0; i < TM; i++)
#pragma unroll
        for (int j = 0; j < TN; j++) acc[i][j] = 0.f;

    for (int k0 = 0; k0 < Kdim; k0 += BK) {
#pragma unroll
        for (int l = 0; l < 2; l++) {
            int f = tid + l * 256;
            int row = f >> 2, kq = f & 3;
            float4 a;
            if (m0 + row < M)
                a = *reinterpret_cast<const float4*>(&A[(long)(m0 + row) * Kdim + k0 + kq * 4]);
            else
                a = make_float4(0.f, 0.f, 0.f, 0.f);
            As[kq * 4 + 0][row] = a.x;
            As[kq * 4 + 1][row] = a.y;
            As[kq * 4 + 2][row] = a.z;
            As[kq * 4 + 3][row] = a.w;
        }
#pragma unroll
        for (int l = 0; l < 2; l++) {
            int f = tid + l * 256;
            int n = f >> 2, kq = f & 3;
            float4 b = *reinterpret_cast<const float4*>(&W[(long)n * Kdim + k0 + kq * 4]);
            Bs[kq * 4 + 0][n] = b.x;
            Bs[kq * 4 + 1][n] = b.y;
            Bs[kq * 4 + 2][n] = b.z;
            Bs[kq * 4 + 3][n] = b.w;
        }
        __syncthreads();
#pragma unroll
        for (int kk = 0; kk < BK; kk++) {
            float a[TM], b[TN];
            *(float4*)&a[0] = *(const float4*)&As[kk][ty * TM];
            *(float4*)&a[4] = *(const float4*)&As[kk][ty * TM + 4];
            *(float4*)&b[0] = *(const float4*)&Bs[kk][tx * TN];
            *(float4*)&b[4] = *(const float4*)&Bs[kk][tx * TN + 4];
#pragma unroll
            for (int i = 0; i < TM; i++)
#pragma unroll
                for (int j = 0; j < TN; j++) acc[i][j] += a[i] * b[j];
        }
        __syncthreads();
    }

    if (MODE == 0) {
        float bvals[TN];
#pragma unroll
        for (int j = 0; j < TN; j++) bvals[j] = bias[tx * TN + j];
#pragma unroll
        for (int i = 0; i < TM; i++) {
            int m = m0 + ty * TM + i;
            if (m < M) {
                float tmp[TN];
#pragma unroll
                for (int j = 0; j < TN; j++) tmp[j] = fmaxf(acc[i][j] + bvals[j], 0.f);
                *(float4*)&Cf[(long)m * CCH + tx * TN]     = *(float4*)&tmp[0];
                *(float4*)&Cf[(long)m * CCH + tx * TN + 4] = *(float4*)&tmp[4];
            }
        }
    } else {
#pragma unroll
        for (int i = 0; i < TM; i++) {
            int m = m0 + ty * TM + i;
            if (m < M) {
                float di = dinv[m];
                unsigned p[4];
#pragma unroll
                for (int jj = 0; jj < 4; jj++)
                    p[jj] = packbf2(acc[i][2 * jj] * di, acc[i][2 * jj + 1] * di);
                *(uint4*)&Cq[(long)m * (CCH / 2) + tx * 4] = *(uint4*)&p[0];
            }
        }
    }
}

// ---------------- degree / CSR build ----------------
__global__ void zero_cnt(int* cnt, int N) {
    int i = blockIdx.x * 256 + threadIdx.x;
    if (i < N) cnt[i] = 0;
}

__global__ void count_deg(const int* __restrict__ dst, int* __restrict__ cnt, int E) {
    int e = blockIdx.x * 256 + threadIdx.x;
    if (e < E) atomicAdd(&cnt[dst[e]], 1);
}

__global__ void chunk_reduce(const int* __restrict__ cnt, int* __restrict__ csums, int N) {
    __shared__ int s[256];
    int t = threadIdx.x;
    int base = blockIdx.x * 512;
    int a = (base + t < N) ? cnt[base + t] : 0;
    int b = (base + 256 + t < N) ? cnt[base + 256 + t] : 0;
    s[t] = a + b;
    __syncthreads();
    for (int off = 128; off > 0; off >>= 1) {
        if (t < off) s[t] += s[t + off];
        __syncthreads();
    }
    if (t == 0) csums[blockIdx.x] = s[0];
}

__global__ void scan_chunks(const int* __restrict__ csums, int* __restrict__ coffs, int nchunks) {
    __shared__ int s[256];
    int t = threadIdx.x;
    int v = (t < nchunks) ? csums[t] : 0;
    s[t] = v;
    __syncthreads();
    for (int off = 1; off < 256; off <<= 1) {
        int x = (t >= off) ? s[t - off] : 0;
        __syncthreads();
        s[t] += x;
        __syncthreads();
    }
    if (t < nchunks) coffs[t] = s[t] - v;  // exclusive
}

__global__ __launch_bounds__(512)
void scan_within(const int* __restrict__ cnt, const int* __restrict__ coffs,
                 int* __restrict__ row_start, int* __restrict__ row_cur,
                 float* __restrict__ dinv, int N)
{
    __shared__ int s[512];
    int t = threadIdx.x;
    int i = blockIdx.x * 512 + t;
    int v = (i < N) ? cnt[i] : 0;
    s[t] = v;
    __syncthreads();
    for (int off = 1; off < 512; off <<= 1) {
        int x = (t >= off) ? s[t - off] : 0;
        __syncthreads();
        s[t] += x;
        __syncthreads();
    }
    if (i < N) {
        int excl = coffs[blockIdx.x] + s[t] - v;
        row_start[i] = excl;
        row_cur[i] = excl;
        dinv[i] = rsqrtf((float)v + 1.0f);   // deg = in-degree + self-loop >= 1
    }
}

__global__ void fill_csr(const int* __restrict__ src, const int* __restrict__ dst,
                         int* __restrict__ row_cur, int* __restrict__ csr, int E)
{
    int e = blockIdx.x * 256 + threadIdx.x;
    if (e < E) {
        int d = dst[e];
        int slot = atomicAdd(&row_cur[d], 1);
        csr[slot] = src[e];
    }
}

// ---------------- gather: out[n] = b2 + dinv[n]*(z'[n] + sum_in z'[s]) ----------------
// z' is packed bf16x2, row = 64 uints. One wave per node; lane owns channels 2*lane, 2*lane+1.
__global__ __launch_bounds__(256)
void gather_nodes(const unsigned* __restrict__ zq, const int* __restrict__ csr,
                  const int* __restrict__ row_start, const int* __restrict__ cnt,
                  const float* __restrict__ dinv, const float* __restrict__ b2,
                  float* __restrict__ out, int N)
{
    const int node = blockIdx.x * 4 + (threadIdx.x >> 6);
    const int lane = threadIdx.x & 63;
    if (node >= N) return;

    // self term (z' already includes dinv[node] factor)
    float2 zs = bf2f2(zq[(long)node * 64 + lane]);
    float acc0 = zs.x, acc1 = zs.y;

    const int rs = row_start[node];
    const int ce = cnt[node];
    int j = 0;
    for (; j + 4 <= ce; j += 4) {
        int s0 = csr[rs + j + 0];
        int s1 = csr[rs + j + 1];
        int s2 = csr[rs + j + 2];
        int s3 = csr[rs + j + 3];
        unsigned a = zq[(long)s0 * 64 + lane];
        unsigned b = zq[(long)s1 * 64 + lane];
        unsigned c = zq[(long)s2 * 64 + lane];
        unsigned d = zq[(long)s3 * 64 + lane];
        float2 fa = bf2f2(a), fb = bf2f2(b), fc = bf2f2(c), fd = bf2f2(d);
        acc0 += (fa.x + fb.x) + (fc.x + fd.x);
        acc1 += (fa.y + fb.y) + (fc.y + fd.y);
    }
    for (; j < ce; j++) {
        int s = csr[rs + j];
        float2 f = bf2f2(zq[(long)s * 64 + lane]);
        acc0 += f.x;
        acc1 += f.y;
    }

    float di = dinv[node];
    float2 o;
    o.x = b2[lane * 2 + 0] + di * acc0;
    o.y = b2[lane * 2 + 1] + di * acc1;
    *(float2*)&out[(long)node * CCH + lane * 2] = o;
}

extern "C" void kernel_launch(void* const* d_in, const int* in_sizes, int n_in,
                              void* d_out, int out_size, void* d_ws, size_t ws_size,
                              hipStream_t stream)
{
    const float* x  = (const float*)d_in[0];
    const int*   ei = (const int*)d_in[1];
    const float* W1 = (const float*)d_in[2];
    const float* b1 = (const float*)d_in[3];
    const float* W2 = (const float*)d_in[4];
    const float* b2 = (const float*)d_in[5];
    float* out = (float*)d_out;

    const int N = in_sizes[0] / F_IN;
    const int E = in_sizes[1] / 2;
    const int* src = ei;
    const int* dst = ei + E;

    char* ws = (char*)d_ws;
    float* h      = (float*)ws;    ws += (size_t)N * CCH * 4;
    unsigned* zq  = (unsigned*)ws; ws += (size_t)N * (CCH / 2) * 4;
    int* csr      = (int*)ws;      ws += (size_t)E * 4;
    int* cnt      = (int*)ws;      ws += (size_t)N * 4;
    int* rstart   = (int*)ws;      ws += (size_t)N * 4;
    int* rcur     = (int*)ws;      ws += (size_t)N * 4;
    float* dinv   = (float*)ws;    ws += (size_t)N * 4;
    int* csums    = (int*)ws;      ws += 4096;
    int* coffs    = (int*)ws;      ws += 4096;

    const int nchunks = (N + 511) / 512;   // 196 for N=100000

    // degree + CSR build (dinv must be ready before GEMM2's epilogue)
    zero_cnt<<<(N + 255) / 256, 256, 0, stream>>>(cnt, N);
    count_deg<<<(E + 255) / 256, 256, 0, stream>>>(dst, cnt, E);
    chunk_reduce<<<nchunks, 256, 0, stream>>>(cnt, csums, N);
    scan_chunks<<<1, 256, 0, stream>>>(csums, coffs, nchunks);
    scan_within<<<nchunks, 512, 0, stream>>>(cnt, coffs, rstart, rcur, dinv, N);
    fill_csr<<<(E + 255) / 256, 256, 0, stream>>>(src, dst, rcur, csr, E);

    // h = relu(x @ W1^T + b1)  [fp32]
    gemm_tiled<0><<<(N + BM - 1) / BM, 256, 0, stream>>>(x, W1, b1, nullptr, h, nullptr, N, F_IN);
    // z' = (h @ W2^T) * dinv   [packed bf16]
    gemm_tiled<1><<<(N + BM - 1) / BM, 256, 0, stream>>>(h, W2, nullptr, dinv, nullptr, zq, N, CCH);

    // aggregate
    gather_nodes<<<(N + 3) / 4, 256, 0, stream>>>(zq, csr, rstart, cnt, dinv, b2, out, N);
}